// Round 11
// baseline (125.269 us; speedup 1.0000x reference)
//
#include <hip/hip_runtime.h>
#include <hip/hip_bf16.h>

// Problem constants (N,C,H,W = 16,64,56,56)
constexpr int N_ = 16, C_ = 64, CH_ = 32;
constexpr int S_ = 3136;          // H*W
constexpr int SB = 64;            // s-tile
constexpr int NB = S_ / SB;       // 49 tiles per batch
constexpr float SCALE = 0.17677669529663687f;        // 1/sqrt(32)
constexpr float LOG2E = 1.4426950408889634f;
constexpr float SCALE2 = SCALE * LOG2E;              // theta pre-scale (exp2 fold)
constexpr float FIXM2 = 16.0f * LOG2E;               // fixed max in exp2 domain

using f32x4 = __attribute__((ext_vector_type(4))) float;
using bf16x8 = __attribute__((ext_vector_type(8))) short;
using u32x2 = __attribute__((ext_vector_type(2))) unsigned;
using u32x4 = __attribute__((ext_vector_type(4))) unsigned;

// v_cvt_pk_bf16_f32: dst = {bf16(hi), bf16(lo)} in one VALU op (RNE)
__device__ __forceinline__ unsigned cvtpk(float lo, float hi) {
  unsigned r;
  asm("v_cvt_pk_bf16_f32 %0, %1, %2" : "=v"(r) : "v"(lo), "v"(hi));
  return r;
}
// v_exp_f32: 2^x
__device__ __forceinline__ float exp2a(float x) {
  float r;
  asm("v_exp_f32 %0, %1" : "=v"(r) : "v"(x));
  return r;
}
__device__ __forceinline__ unsigned short f2bf(float f) {
  unsigned int u = __builtin_bit_cast(unsigned int, f);
  u += 0x7fffu + ((u >> 16) & 1u);
  return (unsigned short)(u >> 16);
}

// ---------------- Kernel 1: theta/phi (bf16, [N,S,32]) + x->bf16 ([N,C,S]) --
__global__ __launch_bounds__(256)
void prep_kernel(const float* __restrict__ x,
                 const float* __restrict__ w1, const float* __restrict__ b1,
                 const float* __restrict__ w2, const float* __restrict__ b2,
                 unsigned short* __restrict__ thetaT,
                 unsigned short* __restrict__ phiT,
                 unsigned short* __restrict__ xbf) {
  __shared__ float xl[64][68];   // stride 68: rows 16B-aligned
  __shared__ __align__(16) unsigned short thL[64][40];
  __shared__ __align__(16) unsigned short phL[64][40];
  const int b = blockIdx.x;
  const int n = b / NB;
  const int s0 = (b % NB) * SB;
  const int tid = threadIdx.x;
  const int sl = tid & 63;
  const int grp = tid >> 6;

#pragma unroll
  for (int cc = 0; cc < 4; ++cc) {
    int c = cc * 16 + grp * 4 + (sl >> 4);
    int s4 = (sl & 15) * 4;
    size_t gidx = (size_t)(n * C_ + c) * S_ + s0 + s4;
    f32x4 v = *(const f32x4*)(x + gidx);
    *(f32x4*)&xl[c][s4] = v;
    u32x2 pb;
    pb.x = cvtpk(v[0], v[1]);
    pb.y = cvtpk(v[2], v[3]);
    *(u32x2*)(xbf + gidx) = pb;
  }
  __syncthreads();

  float acc1[8], acc2[8];
  const int i0u = __builtin_amdgcn_readfirstlane(grp * 8);
  const float* w1b = w1 + i0u * C_;
  const float* w2b = w2 + i0u * C_;
#pragma unroll
  for (int ii = 0; ii < 8; ++ii) {
    acc1[ii] = b1[i0u + ii];
    acc2[ii] = b2[i0u + ii];
  }
#pragma unroll 1
  for (int cc = 0; cc < 4; ++cc) {
    float xv[16];
#pragma unroll
    for (int k = 0; k < 16; ++k) xv[k] = xl[cc * 16 + k][sl];
#pragma unroll
    for (int ii = 0; ii < 8; ++ii) {
#pragma unroll
      for (int k = 0; k < 16; ++k) {
        acc1[ii] = fmaf(w1b[ii * C_ + cc * 16 + k], xv[k], acc1[ii]);
        acc2[ii] = fmaf(w2b[ii * C_ + cc * 16 + k], xv[k], acc2[ii]);
      }
    }
  }
  {
    u32x4 t4, p4;
    t4.x = cvtpk(acc1[0] * SCALE2, acc1[1] * SCALE2);
    t4.y = cvtpk(acc1[2] * SCALE2, acc1[3] * SCALE2);
    t4.z = cvtpk(acc1[4] * SCALE2, acc1[5] * SCALE2);
    t4.w = cvtpk(acc1[6] * SCALE2, acc1[7] * SCALE2);
    p4.x = cvtpk(acc2[0], acc2[1]);
    p4.y = cvtpk(acc2[2], acc2[3]);
    p4.z = cvtpk(acc2[4], acc2[5]);
    p4.w = cvtpk(acc2[6], acc2[7]);
    *(u32x4*)&thL[sl][grp * 8] = t4;
    *(u32x4*)&phL[sl][grp * 8] = p4;
  }
  __syncthreads();
  {
    int row = tid >> 2, ch = (tid & 3) * 8;
    size_t o = ((size_t)(n * S_) + s0 + row) * CH_ + ch;
    *(bf16x8*)(thetaT + o) = *(const bf16x8*)&thL[row][ch];
    *(bf16x8*)(phiT + o)   = *(const bf16x8*)&phL[row][ch];
  }
}

// ---------------- Kernel 2: attn (8 waves, intra-block t-split) + conv3 ----
// Waves w=0..7: qw=w&3 owns 16 q-rows, th=w>>2 owns even/odd tile of each
// 128-t pair. Fixed-max softmax => th-merge is additive (LDS overlay on ldsV).
__global__ __launch_bounds__(512)
void attn_kernel(const unsigned short* __restrict__ thetaT,
                 const unsigned short* __restrict__ phiT,
                 const unsigned short* __restrict__ xbf,
                 const float* __restrict__ w3, const float* __restrict__ b3,
                 unsigned short* __restrict__ yb, float* __restrict__ partials) {
  __shared__ __align__(16) unsigned short ldsK[2][64 * 40];  // pair of K tiles
  __shared__ __align__(16) unsigned short ldsV[2][64 * 72];  // pair of V tiles
  __shared__ float redS[4][128];
  // XCD swizzle: 784 = 8*98
  const int b = (blockIdx.x & 7) * 98 + (blockIdx.x >> 3);
  const int n = b / NB;
  const int q0 = (b % NB) * SB;
  const int tid = threadIdx.x;
  const int lane = tid & 63;
  const int w = tid >> 6;
  const int qw = w & 3;
  const int th = w >> 2;
  const int l16 = lane & 15;
  const int g = lane >> 4;

  const bf16x8 qf = *(const bf16x8*)(thetaT + ((size_t)(n * S_) + q0 + qw * 16 + l16) * CH_ + g * 8);

  f32x4 oacc[4];
#pragma unroll
  for (int r = 0; r < 4; ++r) oacc[r] = (f32x4){0.f, 0.f, 0.f, 0.f};
  float lsum = 0.f;
  const f32x4 cinit = (f32x4){-FIXM2, -FIXM2, -FIXM2, -FIXM2};

  const unsigned short* phiB = phiT + (size_t)n * S_ * CH_;
  const unsigned short* vB = xbf + (size_t)n * C_ * S_;

  // staging geometry: 512 threads stage a 2-tile pair; 3 b128 per thread
  const int sh = tid >> 8;              // which tile of the pair
  const int st = tid & 255;
  const int krow = st >> 2, kch = (st & 3) * 8;
  const int vc = st >> 3, vch = (st & 7) * 8;

  bf16x8 kst, vst0, vst1;
  {  // prologue: stage pair {0, 64}
    const int t0s = sh * 64;
    kst = *(const bf16x8*)(phiB + (size_t)(t0s + krow) * CH_ + kch);
    vst0 = *(const bf16x8*)(vB + (size_t)vc * S_ + t0s + vch);
    vst1 = *(const bf16x8*)(vB + (size_t)(vc + 32) * S_ + t0s + vch);
    *(bf16x8*)(ldsK[sh] + krow * 40 + kch) = kst;
    *(bf16x8*)(ldsV[sh] + vc * 72 + vch) = vst0;
    *(bf16x8*)(ldsV[sh] + (vc + 32) * 72 + vch) = vst1;
  }
  __syncthreads();

#pragma unroll 1
  for (int pb = 0; pb < S_; pb += 128) {
    const int tpre = pb + 128 + sh * 64;  // prefetch tile (uniform per wave)
    const bool pre = tpre < S_;
    if (pre) {  // T14: issue next-pair global loads before compute
      kst = *(const bf16x8*)(phiB + (size_t)(tpre + krow) * CH_ + kch);
      vst0 = *(const bf16x8*)(vB + (size_t)vc * S_ + tpre + vch);
      vst1 = *(const bf16x8*)(vB + (size_t)(vc + 32) * S_ + tpre + vch);
    }

    const int t0 = pb + th * 64;
    if (t0 < S_) {  // uniform per wave
      const unsigned short* Kc = ldsK[th];
      const unsigned short* Vc = ldsV[th];
      f32x4 st4[4];
      __builtin_amdgcn_s_setprio(1);
#pragma unroll
      for (int tt = 0; tt < 4; ++tt) {
        bf16x8 kf = *(const bf16x8*)(Kc + (tt * 16 + l16) * 40 + g * 8);
        st4[tt] = __builtin_amdgcn_mfma_f32_16x16x32_bf16(kf, qf, cinit, 0, 0, 0);
      }
      __builtin_amdgcn_s_setprio(0);

      u32x2 pk[4];
#pragma unroll
      for (int tt = 0; tt < 4; ++tt) {
        float p0 = exp2a(st4[tt][0]);
        float p1 = exp2a(st4[tt][1]);
        float p2 = exp2a(st4[tt][2]);
        float p3 = exp2a(st4[tt][3]);
        lsum += (p0 + p1) + (p2 + p3);
        pk[tt].x = cvtpk(p0, p1);
        pk[tt].y = cvtpk(p2, p3);
      }

      // PV with permuted k-axis sigma_h(8g+4a+r)=32h+16a+4g+r (P lane-local)
      __builtin_amdgcn_s_setprio(1);
#pragma unroll
      for (int h = 0; h < 2; ++h) {
        bf16x8 pf = __builtin_bit_cast(bf16x8,
            (u32x4){pk[2 * h].x, pk[2 * h].y, pk[2 * h + 1].x, pk[2 * h + 1].y});
#pragma unroll
        for (int ct = 0; ct < 4; ++ct) {
          const unsigned short* vrow = Vc + (ct * 16 + l16) * 72 + 32 * h + 4 * g;
          u32x2 v0 = *(const u32x2*)(vrow);
          u32x2 v1 = *(const u32x2*)(vrow + 16);
          bf16x8 vf = __builtin_bit_cast(bf16x8, (u32x4){v0.x, v0.y, v1.x, v1.y});
          oacc[ct] = __builtin_amdgcn_mfma_f32_16x16x32_bf16(vf, pf, oacc[ct], 0, 0, 0);
        }
      }
      __builtin_amdgcn_s_setprio(0);
    }

    __syncthreads();  // pair fully consumed
    if (pre) {
      *(bf16x8*)(ldsK[sh] + krow * 40 + kch) = kst;
      *(bf16x8*)(ldsV[sh] + vc * 72 + vch) = vst0;
      *(bf16x8*)(ldsV[sh] + (vc + 32) * 72 + vch) = vst1;
    }
    __syncthreads();  // new pair visible
  }

  // ---- th-merge: additive (fixed-max) via overlay on ldsV (18,432 B) ----
  float* mrg = (float*)&ldsV[0][0];  // [4][64][18] floats
  if (th == 1) {
    float* p = mrg + ((size_t)(qw * 64 + lane)) * 18;
#pragma unroll
    for (int ct = 0; ct < 4; ++ct) *(f32x4*)(p + ct * 4) = oacc[ct];
    p[16] = lsum;
  }
  __syncthreads();
  if (th == 0) {
    float* p = mrg + ((size_t)(qw * 64 + lane)) * 18;
#pragma unroll
    for (int ct = 0; ct < 4; ++ct) oacc[ct] += *(const f32x4*)(p + ct * 4);
    lsum += p[16];

    // denominator for q=l16 (sum over g-groups)
    float lt = lsum;
    lt += __shfl_xor(lt, 16);
    lt += __shfl_xor(lt, 32);
    const float inv = 1.0f / lt;

    // f fragments (bf16, sigma_m(8g+4a+r)=16(2m+a)+4g+r): lane-local
    u32x4 ff[2];
#pragma unroll
    for (int m = 0; m < 2; ++m) {
      ff[m].x = cvtpk(oacc[2 * m][0] * inv, oacc[2 * m][1] * inv);
      ff[m].y = cvtpk(oacc[2 * m][2] * inv, oacc[2 * m][3] * inv);
      ff[m].z = cvtpk(oacc[2 * m + 1][0] * inv, oacc[2 * m + 1][1] * inv);
      ff[m].w = cvtpk(oacc[2 * m + 1][2] * inv, oacc[2 * m + 1][3] * inv);
    }

    // y = W3*f + b3 per 16-co tile; D[co=4g+rd][q=l16]; y stored bf16
    const int q = q0 + qw * 16 + l16;
#pragma unroll
    for (int t = 0; t < 4; ++t) {
      const float* wr = w3 + (t * 16 + l16) * C_;
      f32x4 acc = *(const f32x4*)(b3 + t * 16 + 4 * g);
#pragma unroll
      for (int m = 0; m < 2; ++m) {
        f32x4 A0 = *(const f32x4*)(wr + 32 * m + 4 * g);
        f32x4 A1 = *(const f32x4*)(wr + 32 * m + 16 + 4 * g);
        u32x4 wf;
        wf.x = cvtpk(A0[0], A0[1]);
        wf.y = cvtpk(A0[2], A0[3]);
        wf.z = cvtpk(A1[0], A1[1]);
        wf.w = cvtpk(A1[2], A1[3]);
        acc = __builtin_amdgcn_mfma_f32_16x16x32_bf16(
            __builtin_bit_cast(bf16x8, wf), __builtin_bit_cast(bf16x8, ff[m]),
            acc, 0, 0, 0);
      }
#pragma unroll
      for (int rd = 0; rd < 4; ++rd) {
        const int co = t * 16 + 4 * g + rd;
        float yv = acc[rd];
        yb[(size_t)(n * C_ + co) * S_ + q] = f2bf(yv);
        float s1 = yv, s2 = yv * yv;
#pragma unroll
        for (int off = 1; off < 16; off <<= 1) {
          s1 += __shfl_xor(s1, off);
          s2 += __shfl_xor(s2, off);
        }
        if (l16 == 0) {
          redS[qw][co] = s1;
          redS[qw][64 + co] = s2;
        }
      }
    }
  }
  __syncthreads();
  if (tid < 128)
    partials[(size_t)b * 128 + tid] =
        redS[0][tid] + redS[1][tid] + redS[2][tid] + redS[3][tid];
}

// ---------------- Kernel 3: reduce partials -> stats[128], parallel --------
__global__ __launch_bounds__(256)
void stats_kernel(const float* __restrict__ partials, float* __restrict__ stats) {
  __shared__ float red[4];
  const int c = blockIdx.x;        // 0..127
  const int tid = threadIdx.x;
  float s = 0.f;
  for (int r = tid; r < N_ * NB; r += 256) s += partials[(size_t)r * 128 + c];
#pragma unroll
  for (int off = 1; off < 64; off <<= 1) s += __shfl_xor(s, off);
  if ((tid & 63) == 0) red[tid >> 6] = s;
  __syncthreads();
  if (tid == 0) stats[c] = red[0] + red[1] + red[2] + red[3];
}

// ---------------- Kernel 4: BN normalize + residual (8 elems/thread) -------
__global__ __launch_bounds__(256)
void bn_kernel(const float* __restrict__ x, const unsigned short* __restrict__ yb,
               const float* __restrict__ stats,
               const float* __restrict__ gamma, const float* __restrict__ beta,
               float* __restrict__ out) {
  const int idx = blockIdx.x * 256 + threadIdx.x;  // 8-elem index
  const size_t base = (size_t)idx * 8;
  const int c = (int)((base / S_) & 63);
  constexpr float invcnt = 1.0f / (N_ * S_);
  float mean = stats[c] * invcnt;
  float var = stats[64 + c] * invcnt - mean * mean;
  float a = gamma[c] * rsqrtf(var + 1e-5f);
  float bb = beta[c] - mean * a;
  u32x4 yv = *(const u32x4*)(yb + base);
#pragma unroll
  for (int h = 0; h < 2; ++h) {
    f32x4 xv = *(const f32x4*)(x + base + h * 4);
    f32x4 o;
#pragma unroll
    for (int r = 0; r < 2; ++r) {
      unsigned packed = (h * 2 + r == 0) ? yv.x : (h * 2 + r == 1) ? yv.y
                        : (h * 2 + r == 2) ? yv.z : yv.w;
      float ylo = __builtin_bit_cast(float, packed << 16);
      float yhi = __builtin_bit_cast(float, packed & 0xffff0000u);
      o[r * 2 + 0] = fmaf(ylo, a, xv[r * 2 + 0] + bb);
      o[r * 2 + 1] = fmaf(yhi, a, xv[r * 2 + 1] + bb);
    }
    *(f32x4*)(out + base + h * 4) = o;
  }
}

// ---------------- launcher -------------------------------------------------
extern "C" void kernel_launch(void* const* d_in, const int* in_sizes, int n_in,
                              void* d_out, int out_size, void* d_ws, size_t ws_size,
                              hipStream_t stream) {
  const float* x = (const float*)d_in[0];
  const float* w1 = (const float*)d_in[1];
  const float* b1 = (const float*)d_in[2];
  const float* w2 = (const float*)d_in[3];
  const float* b2 = (const float*)d_in[4];
  const float* w3 = (const float*)d_in[5];
  const float* b3 = (const float*)d_in[6];
  const float* gamma = (const float*)d_in[7];
  const float* beta = (const float*)d_in[8];

  char* ws = (char*)d_ws;
  unsigned short* thetaT = (unsigned short*)(ws + 0);          //  3,211,264
  unsigned short* phiT   = (unsigned short*)(ws + 3211264);    //  3,211,264
  unsigned short* xbf    = (unsigned short*)(ws + 6422528);    //  6,422,528
  unsigned short* yb     = (unsigned short*)(ws + 12845056);   //  6,422,528
  float* stats           = (float*)(ws + 19267584);            //        512
  float* partials        = (float*)(ws + 19268096);            //    401,408
  if (ws_size < 19669504) return;  // fail loudly rather than corrupt

  prep_kernel<<<N_ * NB, 256, 0, stream>>>(x, w1, b1, w2, b2, thetaT, phiT, xbf);
  attn_kernel<<<N_ * NB, 512, 0, stream>>>(thetaT, phiT, xbf, w3, b3, yb, partials);
  stats_kernel<<<128, 256, 0, stream>>>(partials, stats);
  bn_kernel<<<(out_size / 8) / 256, 256, 0, stream>>>(x, yb, stats, gamma, beta, (float*)d_out);
}